// Round 2
// baseline (6454.984 us; speedup 1.0000x reference)
//
#include <hip/hip_runtime.h>
#include <math.h>

#define Bn 256
#define Tn 300
#define Nn 512
#define NB 64
#define LDV 68   // stream/Vd pitch: breaks 16-row stride conflicts (measured 0 conflicts R1)
#define LDA 65   // diag-Cholesky pitch

#define TOFF(i,j) ((size_t)((i)*NB)*Nn + (size_t)(j)*NB)

// ---- helpers (512-thread tile ops; per-wave access shape identical to the
// 256-thread version: 4 row-groups x 16 col-lanes per wave) -----------------
__device__ __forceinline__ void load_tile_f4(const float* __restrict__ g, int tid, float4 r[2]) {
#pragma unroll
  for (int t = 0; t < 2; t++) {
    int q = tid + 512 * t;          // f4 index 0..1023
    int row = q >> 4, c4 = q & 15;  // 64 rows x 16 float4
    r[t] = ((const float4*)(g + (size_t)row * Nn))[c4];
  }
}
__device__ __forceinline__ void store_stage(float* __restrict__ s, int tid, const float4 r[2]) {
#pragma unroll
  for (int t = 0; t < 2; t++) {
    int q = tid + 512 * t;
    int row = q >> 4, c4 = q & 15;
    *((float4*)(s + row * LDV + c4 * 4)) = r[t];
  }
}
// acc -= Arows · Brows^T (64-deep), 2x4 frag at (tr*2.., tc+16*..)
__device__ __forceinline__ void mm_nt_sub(const float* __restrict__ sa, const float* __restrict__ sb,
                                          int tr, int tc, float acc[2][4]) {
  for (int k = 0; k < NB; k += 4) {
    float4 av[2], bv[4];
#pragma unroll
    for (int i = 0; i < 2; i++) av[i] = *(const float4*)(sa + (tr * 2 + i) * LDV + k);
#pragma unroll
    for (int j = 0; j < 4; j++) bv[j] = *(const float4*)(sb + (tc + 16 * j) * LDV + k);
#pragma unroll
    for (int i = 0; i < 2; i++)
#pragma unroll
      for (int j = 0; j < 4; j++)
        acc[i][j] -= av[i].x * bv[j].x + av[i].y * bv[j].y + av[i].z * bv[j].z + av[i].w * bv[j].w;
  }
}

// K1: gamma[b,d] = sum_t x[b,t,d]*w[b,t]; Nsum[b] = sum_t w[b,t]
__global__ __launch_bounds__(256) void k_gamma(const float* __restrict__ x,
                                               const float* __restrict__ w,
                                               float* __restrict__ gamma,
                                               float* __restrict__ Nsum) {
  int b = blockIdx.x, tid = threadIdx.x;
  const float2* xb = (const float2*)(x + (size_t)b * Tn * Nn);
  const float* wb = w + b * Tn;
  float gx = 0.f, gy = 0.f, ns = 0.f;
  for (int t = 0; t < Tn; t++) {
    float wt = wb[t];
    ns += wt;
    float2 v = xb[(size_t)t * 256 + tid];
    gx += v.x * wt;
    gy += v.y * wt;
  }
  float2 g2; g2.x = gx; g2.y = gy;
  ((float2*)(gamma + b * Nn))[tid] = g2;
  if (tid == 0) Nsum[b] = ns;
}

// K2: C = diag(exp(0.5*Dw)) * chol_w, full store with explicit zeros below diag
__global__ __launch_bounds__(256) void k_prepC(const float* __restrict__ Dw,
                                               const float* __restrict__ cholw,
                                               float* __restrict__ C) {
  int r = blockIdx.x, tid = threadIdx.x;
  float s = expf(0.5f * Dw[r]);
  for (int c = tid; c < Nn; c += 256)
    C[r * Nn + c] = (c >= r) ? s * cholw[r * Nn + c] : 0.f;
}

// K3: CCT = C*C^T. Upper 32x32 tiles (136) + the 8 below-diagonal tiles adjacent
// to the 64x64 diagonal blocks (needed by k_factor's full-tile reads).
__global__ __launch_bounds__(256) void k_cct(const float* __restrict__ C,
                                             float* __restrict__ CCT) {
  __shared__ float Ci[32][33];
  __shared__ float Cj[32][33];
  int tid = threadIdx.x;
  int idx = blockIdx.x, ti = 0, tj;
  if (idx < 136) {
    while (idx >= 16 - ti) { idx -= 16 - ti; ti++; }
    tj = ti + idx;
  } else {                 // lower sub-tile of 64x64 diag block j: (2j+1, 2j)
    ti = 2 * (idx - 136) + 1;
    tj = ti - 1;
  }
  int i0 = ti * 32, j0 = tj * 32;
  int m0 = (i0 > j0) ? i0 : j0;
  float acc[4] = {0.f, 0.f, 0.f, 0.f};
  int r = tid >> 3, c0 = tid & 7;
  for (int kt = m0; kt < Nn; kt += 32) {  // C rows are zero left of the diagonal
    __syncthreads();
    for (int q = tid; q < 1024; q += 256) {
      int rr = q >> 5, cc = q & 31;
      Ci[rr][cc] = C[(size_t)(i0 + rr) * Nn + kt + cc];
      Cj[rr][cc] = C[(size_t)(j0 + rr) * Nn + kt + cc];
    }
    __syncthreads();
    for (int k = 0; k < 32; k++) {
      float a = Ci[r][k];
#pragma unroll
      for (int j = 0; j < 4; j++) acc[j] += a * Cj[c0 + 8 * j][k];
    }
  }
#pragma unroll
  for (int j = 0; j < 4; j++)
    CCT[(size_t)(i0 + r) * Nn + j0 + c0 + 8 * j] = acc[j];
}

// K4 (left-looking, fused trsm): per batch b, reverse-Cholesky S = CCT + Nb*I = U U^T.
// 512 threads (8 waves -> 2 waves/SIMD; LDS caps us at 1 block/CU so block size
// is the only occupancy lever). __launch_bounds__(512, 2): the LDS footprint
// already limits us to 1 block/CU = 2 waves/EU; without the explicit second arg
// the backend targeted 4 waves/EU, capped VGPRs at 128 and spilled (R1: 6.8 GB
// scratch writes). Declaring 2 raises the VGPR budget to 256 -> no spill.
__global__ __launch_bounds__(512, 2) void k_factor(const float* __restrict__ CCT,
                                                   const float* __restrict__ Nsum,
                                                   float* __restrict__ AG) {
  const int b = blockIdx.x, tid = threadIdx.x;
  float* A = AG + (size_t)b * Nn * Nn;
  const float Nb = Nsum[b];
  __shared__ __align__(16) float sA[2][NB * LDV];
  __shared__ __align__(16) float sB[2][NB * LDV];
  __shared__ __align__(16) float sVd[NB * LDV];
  __shared__ float sAd[NB * LDA];
  const int tr = tid >> 4, tc = tid & 15;   // 32 row-groups x 16 col-lanes
  float4 ra[2], rb[2];

  for (int j = 7; j >= 0; j--) {
    const int nst = 7 - j;
    // ---------- diag tile: acc = CCT(j,j)+Nb*I - sum_k U(j,k)U(j,k)^T ----------
    float acc[2][4];
    {
      const float* T = CCT + TOFF(j, j);
#pragma unroll
      for (int i = 0; i < 2; i++) {
        const int r = tr * 2 + i;
#pragma unroll
        for (int jj = 0; jj < 4; jj++) {
          const int c = tc + 16 * jj;
          float v = T[(size_t)r * Nn + c];
          if (r == c) v += Nb;
          acc[i][jj] = v;
        }
      }
    }
    if (nst) load_tile_f4(A + TOFF(j, j + 1), tid, ra);
    __syncthreads();                       // previous phase done with sA/sB
    if (nst) store_stage(sA[0], tid, ra);
    __syncthreads();
    for (int kk = 0; kk < nst; kk++) {
      const int s = kk & 1;
      if (kk + 1 < nst) load_tile_f4(A + TOFF(j, j + 2 + kk), tid, ra);
      mm_nt_sub(sA[s], sA[s], tr, tc, acc);
      if (kk + 1 < nst) store_stage(sA[s ^ 1], tid, ra);
      __syncthreads();
    }
    // deposit to sAd (full tile defined)
#pragma unroll
    for (int i = 0; i < 2; i++)
#pragma unroll
      for (int jj = 0; jj < 4; jj++)
        sAd[(tr * 2 + i) * LDA + tc + 16 * jj] = acc[i][jj];
    __syncthreads();
    // reverse Cholesky of 64x64 (upper): columns high->low
    for (int c = NB - 1; c >= 0; c--) {
      float dcc = sAd[c * LDA + c];
      float rs = rsqrtf(dcc);
      if (tid < c) sAd[tid * LDA + c] *= rs;
      else if (tid == c) sAd[c * LDA + c] = dcc * rs;
      __syncthreads();
      int jj = tid & 63, i0 = tid >> 6;     // i0 0..7 with 512 threads
      if (jj < c) {
        float ujc = sAd[jj * LDA + c];
        for (int i = i0; i <= jj; i += 8) sAd[i * LDA + jj] -= sAd[i * LDA + c] * ujc;
      }
      __syncthreads();
    }
    // Vd = Ujj^-1: zero, then barrier-free per-thread column back-substitution
    for (int q = tid; q < NB * LDV; q += 512) sVd[q] = 0.f;
    __syncthreads();
    if (tid < NB) {
      const int c = tid;  // column c: rows r=c..0, deps are thread-private
      for (int r = c; r >= 0; r--) {
        float s2 = (r == c) ? 1.f : 0.f;
        for (int k = r + 1; k <= c; k++) s2 -= sAd[r * LDA + k] * sVd[k * LDV + c];
        sVd[r * LDV + c] = s2 / sAd[r * LDA + r];
      }
    }
    __syncthreads();
    // stash Vd in a dead lower-triangle tile for k_solve
    {
      const int vr = (j < 7) ? 7 : 6, vc = (j < 7) ? j : 0;
      float* Vt = A + TOFF(vr, vc);
      for (int q = tid; q < NB * NB; q += 512) {
        int r = q >> 6, c = q & 63;
        Vt[(size_t)r * Nn + c] = sVd[r * LDV + c];
      }
    }
    // ---------- off-diag tiles: U(i,j) = (CCT(i,j) - sum_k U(i,k)U(j,k)^T) Vd^T ----------
    for (int i = j - 1; i >= 0; i--) {
      float acc2[2][4];
      {
        const float* T = CCT + TOFF(i, j);
#pragma unroll
        for (int ii = 0; ii < 2; ii++)
#pragma unroll
          for (int jj = 0; jj < 4; jj++)
            acc2[ii][jj] = T[(size_t)(tr * 2 + ii) * Nn + tc + 16 * jj];
      }
      if (nst) {
        load_tile_f4(A + TOFF(i, j + 1), tid, ra);
        load_tile_f4(A + TOFF(j, j + 1), tid, rb);
      }
      __syncthreads();                     // prev readers of sA/sB done
      if (nst) { store_stage(sA[0], tid, ra); store_stage(sB[0], tid, rb); }
      __syncthreads();
      for (int kk = 0; kk < nst; kk++) {
        const int s = kk & 1;
        if (kk + 1 < nst) {
          load_tile_f4(A + TOFF(i, j + 2 + kk), tid, ra);
          load_tile_f4(A + TOFF(j, j + 2 + kk), tid, rb);
        }
        mm_nt_sub(sA[s], sB[s], tr, tc, acc2);
        if (kk + 1 < nst) { store_stage(sA[s ^ 1], tid, ra); store_stage(sB[s ^ 1], tid, rb); }
        __syncthreads();
      }
      // trsm via round trip: X = acc2 · Vd^T
#pragma unroll
      for (int ii = 0; ii < 2; ii++)
#pragma unroll
        for (int jj = 0; jj < 4; jj++)
          sA[0][(tr * 2 + ii) * LDV + tc + 16 * jj] = acc2[ii][jj];
      __syncthreads();
      {
        float out[2][4] = {};
        for (int k = 0; k < NB; k += 4) {
          float4 av[2], bv[4];
#pragma unroll
          for (int ii = 0; ii < 2; ii++) av[ii] = *(const float4*)(sA[0] + (tr * 2 + ii) * LDV + k);
#pragma unroll
          for (int jj = 0; jj < 4; jj++) bv[jj] = *(const float4*)(sVd + (tc + 16 * jj) * LDV + k);
#pragma unroll
          for (int ii = 0; ii < 2; ii++)
#pragma unroll
            for (int jj = 0; jj < 4; jj++)
              out[ii][jj] += av[ii].x * bv[jj].x + av[ii].y * bv[jj].y +
                             av[ii].z * bv[jj].z + av[ii].w * bv[jj].w;
        }
        float* X = A + TOFF(i, j);
#pragma unroll
        for (int ii = 0; ii < 2; ii++)
#pragma unroll
          for (int jj = 0; jj < 4; jj++)
            X[(size_t)(tr * 2 + ii) * Nn + tc + 16 * jj] = out[ii][jj];
      }
      __syncthreads();                     // before next tile reuses sA[0]
    }
  }
}

// K5: per batch, solve U*G = C (G upper) in place over U; Vd read from stash.
// 512 threads, 2x4 fragments, launch_bounds(512,2) (same spill rationale as k_factor).
__global__ __launch_bounds__(512, 2) void k_solve(const float* __restrict__ C,
                                                  float* __restrict__ AG) {
  const int b = blockIdx.x, tid = threadIdx.x;
  float* A = AG + (size_t)b * Nn * Nn;
  __shared__ __align__(16) float sA[2][NB * LDV];
  __shared__ __align__(16) float sB[2][NB * LDV];
  __shared__ __align__(16) float sVd[NB * LDV];
  const int tr = tid >> 4, tc = tid & 15;
  float4 ra[2], rb[2];
  for (int R = 7; R >= 0; R--) {
    {
      const int vr = (R < 7) ? 7 : 6, vc = (R < 7) ? R : 0;
      const float* Vt = A + TOFF(vr, vc);
      __syncthreads();                     // prev R's readers of sVd done
      for (int q = tid; q < NB * NB; q += 512) {
        int r = q >> 6, c = q & 63;
        sVd[r * LDV + c] = Vt[(size_t)r * Nn + c];
      }
      __syncthreads();
    }
    for (int J = 7; J >= R; J--) {
      const int nst = J - R;
      float acc[2][4];
      {
        const float* T = C + TOFF(R, J);
#pragma unroll
        for (int ii = 0; ii < 2; ii++)
#pragma unroll
          for (int jj = 0; jj < 4; jj++)
            acc[ii][jj] = T[(size_t)(tr * 2 + ii) * Nn + tc + 16 * jj];
      }
      if (nst) {
        load_tile_f4(A + TOFF(R, R + 1), tid, ra);
        load_tile_f4(A + TOFF(R + 1, J), tid, rb);
      }
      __syncthreads();
      if (nst) { store_stage(sA[0], tid, ra); store_stage(sB[0], tid, rb); }
      __syncthreads();
      for (int kk = 0; kk < nst; kk++) {
        const int s = kk & 1;
        if (kk + 1 < nst) {
          load_tile_f4(A + TOFF(R, R + 2 + kk), tid, ra);
          load_tile_f4(A + TOFF(R + 2 + kk, J), tid, rb);
        }
        // acc -= U(R,K) * G(K,J)   (A·B: b-side scalar reads, conflict-free)
        for (int k = 0; k < NB; k += 4) {
          float a4[2][4];
#pragma unroll
          for (int ii = 0; ii < 2; ii++) {
            float4 t = *(const float4*)(sA[s] + (tr * 2 + ii) * LDV + k);
            a4[ii][0] = t.x; a4[ii][1] = t.y; a4[ii][2] = t.z; a4[ii][3] = t.w;
          }
#pragma unroll
          for (int k2 = 0; k2 < 4; k2++) {
            float bb[4];
#pragma unroll
            for (int jj = 0; jj < 4; jj++) bb[jj] = sB[s][(k + k2) * LDV + tc + 16 * jj];
#pragma unroll
            for (int ii = 0; ii < 2; ii++)
#pragma unroll
              for (int jj = 0; jj < 4; jj++) acc[ii][jj] -= a4[ii][k2] * bb[jj];
          }
        }
        if (kk + 1 < nst) { store_stage(sA[s ^ 1], tid, ra); store_stage(sB[s ^ 1], tid, rb); }
        __syncthreads();
      }
      // round trip: temp -> sA[0]; G(R,J) = Vd * temp
#pragma unroll
      for (int ii = 0; ii < 2; ii++)
#pragma unroll
        for (int jj = 0; jj < 4; jj++)
          sA[0][(tr * 2 + ii) * LDV + tc + 16 * jj] = acc[ii][jj];
      __syncthreads();
      {
        float out[2][4] = {};
        for (int k = 0; k < NB; k += 4) {
          float v4[2][4];
#pragma unroll
          for (int ii = 0; ii < 2; ii++) {
            float4 t = *(const float4*)(sVd + (tr * 2 + ii) * LDV + k);
            v4[ii][0] = t.x; v4[ii][1] = t.y; v4[ii][2] = t.z; v4[ii][3] = t.w;
          }
#pragma unroll
          for (int k2 = 0; k2 < 4; k2++) {
            float bb[4];
#pragma unroll
            for (int jj = 0; jj < 4; jj++) bb[jj] = sA[0][(k + k2) * LDV + tc + 16 * jj];
#pragma unroll
            for (int ii = 0; ii < 2; ii++)
#pragma unroll
              for (int jj = 0; jj < 4; jj++) out[ii][jj] += v4[ii][k2] * bb[jj];
          }
        }
        float* G = A + TOFF(R, J);
#pragma unroll
        for (int ii = 0; ii < 2; ii++)
#pragma unroll
          for (int jj = 0; jj < 4; jj++)
            G[(size_t)(tr * 2 + ii) * Nn + tc + 16 * jj] = out[ii][jj];
      }
      __syncthreads();
    }
  }
}

// K6: y = G*gamma, mu = G^T y, logvar = 2 log diag(G), chol = G/diag rows,
// zero strict lower. One row per wave; barrier-free shuffle reduce. 8 waves.
__global__ __launch_bounds__(512, 2) void k_finish(const float* __restrict__ gam,
                                                   float* __restrict__ mu,
                                                   float* __restrict__ logvar,
                                                   float* __restrict__ cholG) {
  int b = blockIdx.x, tid = threadIdx.x;
  float* A = cholG + (size_t)b * Nn * Nn;
  __shared__ float gsh[Nn];
  __shared__ float mup[8][Nn];
  for (int c = tid; c < Nn; c += 512) gsh[c] = gam[b * Nn + c];
  __syncthreads();
  int w = tid >> 6, l = tid & 63;
  float mua[8] = {0.f, 0.f, 0.f, 0.f, 0.f, 0.f, 0.f, 0.f};
  for (int i = w; i < Nn; i += 8) {
    const size_t rowo = (size_t)i * Nn;
    float v[8];
    float s = 0.f;
#pragma unroll
    for (int j = 0; j < 8; j++) {
      int c = (j << 6) + l;
      v[j] = A[rowo + c];
      if (c >= i) s += v[j] * gsh[c];
    }
#pragma unroll
    for (int off = 32; off > 0; off >>= 1) s += __shfl_xor(s, off, 64);
    float d = A[rowo + i];
    float rinv = 1.f / d;
    if (l == 0) logvar[b * Nn + i] = 2.f * logf(d);
#pragma unroll
    for (int j = 0; j < 8; j++) {
      int c = (j << 6) + l;
      if (c >= i) mua[j] += v[j] * s;
      float o = (c > i) ? v[j] * rinv : (c == i ? 1.f : 0.f);
      A[rowo + c] = o;
    }
  }
#pragma unroll
  for (int j = 0; j < 8; j++) mup[w][(j << 6) + l] = mua[j];
  __syncthreads();
  for (int c = tid; c < Nn; c += 512)
    mu[b * Nn + c] = mup[0][c] + mup[1][c] + mup[2][c] + mup[3][c] +
                     mup[4][c] + mup[5][c] + mup[6][c] + mup[7][c];
}

extern "C" void kernel_launch(void* const* d_in, const int* in_sizes, int n_in,
                              void* d_out, int out_size, void* d_ws, size_t ws_size,
                              hipStream_t stream) {
  const float* x = (const float*)d_in[0];
  const float* w = (const float*)d_in[1];
  const float* Dw = (const float*)d_in[2];
  const float* cholw = (const float*)d_in[3];
  float* out = (float*)d_out;
  float* mu = out;                  // [B,512]
  float* logvar = out + Bn * Nn;    // [B,512]
  float* chol = out + 2 * Bn * Nn;  // [B,512,512] scratch: U (+Vd stash) -> G -> final
  float* gamma = mu;                // consumed before mu written
  float* Nsum = logvar;             // consumed before logvar written
  float* Cm = (float*)d_ws;
  float* CCT = Cm + Nn * Nn;
  (void)in_sizes; (void)n_in; (void)out_size; (void)ws_size;

  k_gamma<<<Bn, 256, 0, stream>>>(x, w, gamma, Nsum);
  k_prepC<<<Nn, 256, 0, stream>>>(Dw, cholw, Cm);
  k_cct<<<144, 256, 0, stream>>>(Cm, CCT);
  k_factor<<<Bn, 512, 0, stream>>>(CCT, Nsum, chol);
  k_solve<<<Bn, 512, 0, stream>>>(Cm, chol);
  k_finish<<<Bn, 512, 0, stream>>>(gamma, mu, logvar, chol);
}

// Round 3
// 6430.358 us; speedup vs baseline: 1.0038x; 1.0038x over previous
//
#include <hip/hip_runtime.h>
#include <math.h>

#define Bn 256
#define Tn 300
#define Nn 512
#define NB 64
#define LDV 68   // stream/Vd pitch: breaks 16-row stride conflicts (measured 0 conflicts R1)
#define LDA 65   // diag-Cholesky pitch

#define TOFF(i,j) ((size_t)((i)*NB)*Nn + (size_t)(j)*NB)

// ---- helpers (512-thread tile ops; per-wave access shape identical to the
// 256-thread version: 4 row-groups x 16 col-lanes per wave) -----------------
__device__ __forceinline__ void load_tile_f4(const float* __restrict__ g, int tid, float4 r[2]) {
#pragma unroll
  for (int t = 0; t < 2; t++) {
    int q = tid + 512 * t;          // f4 index 0..1023
    int row = q >> 4, c4 = q & 15;  // 64 rows x 16 float4
    r[t] = ((const float4*)(g + (size_t)row * Nn))[c4];
  }
}
__device__ __forceinline__ void store_stage(float* __restrict__ s, int tid, const float4 r[2]) {
#pragma unroll
  for (int t = 0; t < 2; t++) {
    int q = tid + 512 * t;
    int row = q >> 4, c4 = q & 15;
    *((float4*)(s + row * LDV + c4 * 4)) = r[t];
  }
}
// acc -= Arows · Brows^T (64-deep), 2x4 frag at (tr*2.., tc+16*..)
__device__ __forceinline__ void mm_nt_sub(const float* __restrict__ sa, const float* __restrict__ sb,
                                          int tr, int tc, float acc[2][4]) {
  for (int k = 0; k < NB; k += 4) {
    float4 av[2], bv[4];
#pragma unroll
    for (int i = 0; i < 2; i++) av[i] = *(const float4*)(sa + (tr * 2 + i) * LDV + k);
#pragma unroll
    for (int j = 0; j < 4; j++) bv[j] = *(const float4*)(sb + (tc + 16 * j) * LDV + k);
#pragma unroll
    for (int i = 0; i < 2; i++)
#pragma unroll
      for (int j = 0; j < 4; j++)
        acc[i][j] -= av[i].x * bv[j].x + av[i].y * bv[j].y + av[i].z * bv[j].z + av[i].w * bv[j].w;
  }
}

// K1: gamma[b,d] = sum_t x[b,t,d]*w[b,t]; Nsum[b] = sum_t w[b,t]
__global__ __launch_bounds__(256) void k_gamma(const float* __restrict__ x,
                                               const float* __restrict__ w,
                                               float* __restrict__ gamma,
                                               float* __restrict__ Nsum) {
  int b = blockIdx.x, tid = threadIdx.x;
  const float2* xb = (const float2*)(x + (size_t)b * Tn * Nn);
  const float* wb = w + b * Tn;
  float gx = 0.f, gy = 0.f, ns = 0.f;
  for (int t = 0; t < Tn; t++) {
    float wt = wb[t];
    ns += wt;
    float2 v = xb[(size_t)t * 256 + tid];
    gx += v.x * wt;
    gy += v.y * wt;
  }
  float2 g2; g2.x = gx; g2.y = gy;
  ((float2*)(gamma + b * Nn))[tid] = g2;
  if (tid == 0) Nsum[b] = ns;
}

// K2: C = diag(exp(0.5*Dw)) * chol_w, full store with explicit zeros below diag
__global__ __launch_bounds__(256) void k_prepC(const float* __restrict__ Dw,
                                               const float* __restrict__ cholw,
                                               float* __restrict__ C) {
  int r = blockIdx.x, tid = threadIdx.x;
  float s = expf(0.5f * Dw[r]);
  for (int c = tid; c < Nn; c += 256)
    C[r * Nn + c] = (c >= r) ? s * cholw[r * Nn + c] : 0.f;
}

// K3: CCT = C*C^T. Upper 32x32 tiles (136) + the 8 below-diagonal tiles adjacent
// to the 64x64 diagonal blocks (needed by k_factor's full-tile reads).
__global__ __launch_bounds__(256) void k_cct(const float* __restrict__ C,
                                             float* __restrict__ CCT) {
  __shared__ float Ci[32][33];
  __shared__ float Cj[32][33];
  int tid = threadIdx.x;
  int idx = blockIdx.x, ti = 0, tj;
  if (idx < 136) {
    while (idx >= 16 - ti) { idx -= 16 - ti; ti++; }
    tj = ti + idx;
  } else {                 // lower sub-tile of 64x64 diag block j: (2j+1, 2j)
    ti = 2 * (idx - 136) + 1;
    tj = ti - 1;
  }
  int i0 = ti * 32, j0 = tj * 32;
  int m0 = (i0 > j0) ? i0 : j0;
  float acc[4] = {0.f, 0.f, 0.f, 0.f};
  int r = tid >> 3, c0 = tid & 7;
  for (int kt = m0; kt < Nn; kt += 32) {  // C rows are zero left of the diagonal
    __syncthreads();
    for (int q = tid; q < 1024; q += 256) {
      int rr = q >> 5, cc = q & 31;
      Ci[rr][cc] = C[(size_t)(i0 + rr) * Nn + kt + cc];
      Cj[rr][cc] = C[(size_t)(j0 + rr) * Nn + kt + cc];
    }
    __syncthreads();
    for (int k = 0; k < 32; k++) {
      float a = Ci[r][k];
#pragma unroll
      for (int j = 0; j < 4; j++) acc[j] += a * Cj[c0 + 8 * j][k];
    }
  }
#pragma unroll
  for (int j = 0; j < 4; j++)
    CCT[(size_t)(i0 + r) * Nn + j0 + c0 + 8 * j] = acc[j];
}

// K4 (left-looking, fused trsm): per batch b, reverse-Cholesky S = CCT + Nb*I = U U^T.
// 512 threads (8 waves -> 2 waves/SIMD; LDS caps us at 1 block/CU and grid=#CUs,
// so block size is the only occupancy lever).
// __launch_bounds__(512, 1): R1 (default) and R2 ((512,2)) both pinned VGPRs at
// exactly 128 and spilled ~10 GB of scratch per dispatch -- the toolchain treats
// the 2nd arg as min BLOCKS per CU (CUDA semantics): (512,2) -> 16 waves/CU ->
// 4 waves/EU -> cap 128. (512,1) -> 8 waves/CU -> 2 waves/EU -> cap 256, which
// fits this tile structure's ~132-reg demand (R0 measured) with no spill.
__global__ __launch_bounds__(512, 1) void k_factor(const float* __restrict__ CCT,
                                                   const float* __restrict__ Nsum,
                                                   float* __restrict__ AG) {
  const int b = blockIdx.x, tid = threadIdx.x;
  float* A = AG + (size_t)b * Nn * Nn;
  const float Nb = Nsum[b];
  __shared__ __align__(16) float sA[2][NB * LDV];
  __shared__ __align__(16) float sB[2][NB * LDV];
  __shared__ __align__(16) float sVd[NB * LDV];
  __shared__ float sAd[NB * LDA];
  const int tr = tid >> 4, tc = tid & 15;   // 32 row-groups x 16 col-lanes
  float4 ra[2], rb[2];

  for (int j = 7; j >= 0; j--) {
    const int nst = 7 - j;
    // ---------- diag tile: acc = CCT(j,j)+Nb*I - sum_k U(j,k)U(j,k)^T ----------
    float acc[2][4];
    {
      const float* T = CCT + TOFF(j, j);
#pragma unroll
      for (int i = 0; i < 2; i++) {
        const int r = tr * 2 + i;
#pragma unroll
        for (int jj = 0; jj < 4; jj++) {
          const int c = tc + 16 * jj;
          float v = T[(size_t)r * Nn + c];
          if (r == c) v += Nb;
          acc[i][jj] = v;
        }
      }
    }
    if (nst) load_tile_f4(A + TOFF(j, j + 1), tid, ra);
    __syncthreads();                       // previous phase done with sA/sB
    if (nst) store_stage(sA[0], tid, ra);
    __syncthreads();
    for (int kk = 0; kk < nst; kk++) {
      const int s = kk & 1;
      if (kk + 1 < nst) load_tile_f4(A + TOFF(j, j + 2 + kk), tid, ra);
      mm_nt_sub(sA[s], sA[s], tr, tc, acc);
      if (kk + 1 < nst) store_stage(sA[s ^ 1], tid, ra);
      __syncthreads();
    }
    // deposit to sAd (full tile defined)
#pragma unroll
    for (int i = 0; i < 2; i++)
#pragma unroll
      for (int jj = 0; jj < 4; jj++)
        sAd[(tr * 2 + i) * LDA + tc + 16 * jj] = acc[i][jj];
    __syncthreads();
    // reverse Cholesky of 64x64 (upper): columns high->low
    for (int c = NB - 1; c >= 0; c--) {
      float dcc = sAd[c * LDA + c];
      float rs = rsqrtf(dcc);
      if (tid < c) sAd[tid * LDA + c] *= rs;
      else if (tid == c) sAd[c * LDA + c] = dcc * rs;
      __syncthreads();
      int jj = tid & 63, i0 = tid >> 6;     // i0 0..7 with 512 threads
      if (jj < c) {
        float ujc = sAd[jj * LDA + c];
        for (int i = i0; i <= jj; i += 8) sAd[i * LDA + jj] -= sAd[i * LDA + c] * ujc;
      }
      __syncthreads();
    }
    // Vd = Ujj^-1: zero, then barrier-free per-thread column back-substitution
    for (int q = tid; q < NB * LDV; q += 512) sVd[q] = 0.f;
    __syncthreads();
    if (tid < NB) {
      const int c = tid;  // column c: rows r=c..0, deps are thread-private
      for (int r = c; r >= 0; r--) {
        float s2 = (r == c) ? 1.f : 0.f;
        for (int k = r + 1; k <= c; k++) s2 -= sAd[r * LDA + k] * sVd[k * LDV + c];
        sVd[r * LDV + c] = s2 / sAd[r * LDA + r];
      }
    }
    __syncthreads();
    // stash Vd in a dead lower-triangle tile for k_solve
    {
      const int vr = (j < 7) ? 7 : 6, vc = (j < 7) ? j : 0;
      float* Vt = A + TOFF(vr, vc);
      for (int q = tid; q < NB * NB; q += 512) {
        int r = q >> 6, c = q & 63;
        Vt[(size_t)r * Nn + c] = sVd[r * LDV + c];
      }
    }
    // ---------- off-diag tiles: U(i,j) = (CCT(i,j) - sum_k U(i,k)U(j,k)^T) Vd^T ----------
    for (int i = j - 1; i >= 0; i--) {
      float acc2[2][4];
      {
        const float* T = CCT + TOFF(i, j);
#pragma unroll
        for (int ii = 0; ii < 2; ii++)
#pragma unroll
          for (int jj = 0; jj < 4; jj++)
            acc2[ii][jj] = T[(size_t)(tr * 2 + ii) * Nn + tc + 16 * jj];
      }
      if (nst) {
        load_tile_f4(A + TOFF(i, j + 1), tid, ra);
        load_tile_f4(A + TOFF(j, j + 1), tid, rb);
      }
      __syncthreads();                     // prev readers of sA/sB done
      if (nst) { store_stage(sA[0], tid, ra); store_stage(sB[0], tid, rb); }
      __syncthreads();
      for (int kk = 0; kk < nst; kk++) {
        const int s = kk & 1;
        if (kk + 1 < nst) {
          load_tile_f4(A + TOFF(i, j + 2 + kk), tid, ra);
          load_tile_f4(A + TOFF(j, j + 2 + kk), tid, rb);
        }
        mm_nt_sub(sA[s], sB[s], tr, tc, acc2);
        if (kk + 1 < nst) { store_stage(sA[s ^ 1], tid, ra); store_stage(sB[s ^ 1], tid, rb); }
        __syncthreads();
      }
      // trsm via round trip: X = acc2 · Vd^T
#pragma unroll
      for (int ii = 0; ii < 2; ii++)
#pragma unroll
        for (int jj = 0; jj < 4; jj++)
          sA[0][(tr * 2 + ii) * LDV + tc + 16 * jj] = acc2[ii][jj];
      __syncthreads();
      {
        float out[2][4] = {};
        for (int k = 0; k < NB; k += 4) {
          float4 av[2], bv[4];
#pragma unroll
          for (int ii = 0; ii < 2; ii++) av[ii] = *(const float4*)(sA[0] + (tr * 2 + ii) * LDV + k);
#pragma unroll
          for (int jj = 0; jj < 4; jj++) bv[jj] = *(const float4*)(sVd + (tc + 16 * jj) * LDV + k);
#pragma unroll
          for (int ii = 0; ii < 2; ii++)
#pragma unroll
            for (int jj = 0; jj < 4; jj++)
              out[ii][jj] += av[ii].x * bv[jj].x + av[ii].y * bv[jj].y +
                             av[ii].z * bv[jj].z + av[ii].w * bv[jj].w;
        }
        float* X = A + TOFF(i, j);
#pragma unroll
        for (int ii = 0; ii < 2; ii++)
#pragma unroll
          for (int jj = 0; jj < 4; jj++)
            X[(size_t)(tr * 2 + ii) * Nn + tc + 16 * jj] = out[ii][jj];
      }
      __syncthreads();                     // before next tile reuses sA[0]
    }
  }
}

// K5: per batch, solve U*G = C (G upper) in place over U; Vd read from stash.
// 512 threads, 2x4 fragments, launch_bounds(512,1) (same spill rationale as k_factor).
__global__ __launch_bounds__(512, 1) void k_solve(const float* __restrict__ C,
                                                  float* __restrict__ AG) {
  const int b = blockIdx.x, tid = threadIdx.x;
  float* A = AG + (size_t)b * Nn * Nn;
  __shared__ __align__(16) float sA[2][NB * LDV];
  __shared__ __align__(16) float sB[2][NB * LDV];
  __shared__ __align__(16) float sVd[NB * LDV];
  const int tr = tid >> 4, tc = tid & 15;
  float4 ra[2], rb[2];
  for (int R = 7; R >= 0; R--) {
    {
      const int vr = (R < 7) ? 7 : 6, vc = (R < 7) ? R : 0;
      const float* Vt = A + TOFF(vr, vc);
      __syncthreads();                     // prev R's readers of sVd done
      for (int q = tid; q < NB * NB; q += 512) {
        int r = q >> 6, c = q & 63;
        sVd[r * LDV + c] = Vt[(size_t)r * Nn + c];
      }
      __syncthreads();
    }
    for (int J = 7; J >= R; J--) {
      const int nst = J - R;
      float acc[2][4];
      {
        const float* T = C + TOFF(R, J);
#pragma unroll
        for (int ii = 0; ii < 2; ii++)
#pragma unroll
          for (int jj = 0; jj < 4; jj++)
            acc[ii][jj] = T[(size_t)(tr * 2 + ii) * Nn + tc + 16 * jj];
      }
      if (nst) {
        load_tile_f4(A + TOFF(R, R + 1), tid, ra);
        load_tile_f4(A + TOFF(R + 1, J), tid, rb);
      }
      __syncthreads();
      if (nst) { store_stage(sA[0], tid, ra); store_stage(sB[0], tid, rb); }
      __syncthreads();
      for (int kk = 0; kk < nst; kk++) {
        const int s = kk & 1;
        if (kk + 1 < nst) {
          load_tile_f4(A + TOFF(R, R + 2 + kk), tid, ra);
          load_tile_f4(A + TOFF(R + 2 + kk, J), tid, rb);
        }
        // acc -= U(R,K) * G(K,J)   (A·B: b-side scalar reads, conflict-free)
        for (int k = 0; k < NB; k += 4) {
          float a4[2][4];
#pragma unroll
          for (int ii = 0; ii < 2; ii++) {
            float4 t = *(const float4*)(sA[s] + (tr * 2 + ii) * LDV + k);
            a4[ii][0] = t.x; a4[ii][1] = t.y; a4[ii][2] = t.z; a4[ii][3] = t.w;
          }
#pragma unroll
          for (int k2 = 0; k2 < 4; k2++) {
            float bb[4];
#pragma unroll
            for (int jj = 0; jj < 4; jj++) bb[jj] = sB[s][(k + k2) * LDV + tc + 16 * jj];
#pragma unroll
            for (int ii = 0; ii < 2; ii++)
#pragma unroll
              for (int jj = 0; jj < 4; jj++) acc[ii][jj] -= a4[ii][k2] * bb[jj];
          }
        }
        if (kk + 1 < nst) { store_stage(sA[s ^ 1], tid, ra); store_stage(sB[s ^ 1], tid, rb); }
        __syncthreads();
      }
      // round trip: temp -> sA[0]; G(R,J) = Vd * temp
#pragma unroll
      for (int ii = 0; ii < 2; ii++)
#pragma unroll
        for (int jj = 0; jj < 4; jj++)
          sA[0][(tr * 2 + ii) * LDV + tc + 16 * jj] = acc[ii][jj];
      __syncthreads();
      {
        float out[2][4] = {};
        for (int k = 0; k < NB; k += 4) {
          float v4[2][4];
#pragma unroll
          for (int ii = 0; ii < 2; ii++) {
            float4 t = *(const float4*)(sVd + (tr * 2 + ii) * LDV + k);
            v4[ii][0] = t.x; v4[ii][1] = t.y; v4[ii][2] = t.z; v4[ii][3] = t.w;
          }
#pragma unroll
          for (int k2 = 0; k2 < 4; k2++) {
            float bb[4];
#pragma unroll
            for (int jj = 0; jj < 4; jj++) bb[jj] = sA[0][(k + k2) * LDV + tc + 16 * jj];
#pragma unroll
            for (int ii = 0; ii < 2; ii++)
#pragma unroll
              for (int jj = 0; jj < 4; jj++) out[ii][jj] += v4[ii][k2] * bb[jj];
          }
        }
        float* G = A + TOFF(R, J);
#pragma unroll
        for (int ii = 0; ii < 2; ii++)
#pragma unroll
          for (int jj = 0; jj < 4; jj++)
            G[(size_t)(tr * 2 + ii) * Nn + tc + 16 * jj] = out[ii][jj];
      }
      __syncthreads();
    }
  }
}

// K6: y = G*gamma, mu = G^T y, logvar = 2 log diag(G), chol = G/diag rows,
// zero strict lower. One row per wave; barrier-free shuffle reduce. 8 waves.
__global__ __launch_bounds__(512, 1) void k_finish(const float* __restrict__ gam,
                                                   float* __restrict__ mu,
                                                   float* __restrict__ logvar,
                                                   float* __restrict__ cholG) {
  int b = blockIdx.x, tid = threadIdx.x;
  float* A = cholG + (size_t)b * Nn * Nn;
  __shared__ float gsh[Nn];
  __shared__ float mup[8][Nn];
  for (int c = tid; c < Nn; c += 512) gsh[c] = gam[b * Nn + c];
  __syncthreads();
  int w = tid >> 6, l = tid & 63;
  float mua[8] = {0.f, 0.f, 0.f, 0.f, 0.f, 0.f, 0.f, 0.f};
  for (int i = w; i < Nn; i += 8) {
    const size_t rowo = (size_t)i * Nn;
    float v[8];
    float s = 0.f;
#pragma unroll
    for (int j = 0; j < 8; j++) {
      int c = (j << 6) + l;
      v[j] = A[rowo + c];
      if (c >= i) s += v[j] * gsh[c];
    }
#pragma unroll
    for (int off = 32; off > 0; off >>= 1) s += __shfl_xor(s, off, 64);
    float d = A[rowo + i];
    float rinv = 1.f / d;
    if (l == 0) logvar[b * Nn + i] = 2.f * logf(d);
#pragma unroll
    for (int j = 0; j < 8; j++) {
      int c = (j << 6) + l;
      if (c >= i) mua[j] += v[j] * s;
      float o = (c > i) ? v[j] * rinv : (c == i ? 1.f : 0.f);
      A[rowo + c] = o;
    }
  }
#pragma unroll
  for (int j = 0; j < 8; j++) mup[w][(j << 6) + l] = mua[j];
  __syncthreads();
  for (int c = tid; c < Nn; c += 512)
    mu[b * Nn + c] = mup[0][c] + mup[1][c] + mup[2][c] + mup[3][c] +
                     mup[4][c] + mup[5][c] + mup[6][c] + mup[7][c];
}

extern "C" void kernel_launch(void* const* d_in, const int* in_sizes, int n_in,
                              void* d_out, int out_size, void* d_ws, size_t ws_size,
                              hipStream_t stream) {
  const float* x = (const float*)d_in[0];
  const float* w = (const float*)d_in[1];
  const float* Dw = (const float*)d_in[2];
  const float* cholw = (const float*)d_in[3];
  float* out = (float*)d_out;
  float* mu = out;                  // [B,512]
  float* logvar = out + Bn * Nn;    // [B,512]
  float* chol = out + 2 * Bn * Nn;  // [B,512,512] scratch: U (+Vd stash) -> G -> final
  float* gamma = mu;                // consumed before mu written
  float* Nsum = logvar;             // consumed before logvar written
  float* Cm = (float*)d_ws;
  float* CCT = Cm + Nn * Nn;
  (void)in_sizes; (void)n_in; (void)out_size; (void)ws_size;

  k_gamma<<<Bn, 256, 0, stream>>>(x, w, gamma, Nsum);
  k_prepC<<<Nn, 256, 0, stream>>>(Dw, cholw, Cm);
  k_cct<<<144, 256, 0, stream>>>(Cm, CCT);
  k_factor<<<Bn, 512, 0, stream>>>(CCT, Nsum, chol);
  k_solve<<<Bn, 512, 0, stream>>>(Cm, chol);
  k_finish<<<Bn, 512, 0, stream>>>(gamma, mu, logvar, chol);
}

// Round 4
// 2304.171 us; speedup vs baseline: 2.8014x; 2.7907x over previous
//
#include <hip/hip_runtime.h>
#include <math.h>

#define Bn 256
#define Tn 300
#define Nn 512
#define NB 64
#define LDV 68   // stream/Vd pitch: breaks 16-row stride conflicts
#define LDA 65   // diag-Cholesky pitch

#define TOFF(i,j) ((size_t)((i)*NB)*Nn + (size_t)(j)*NB)

// ---- helpers (512-thread tile ops; per-wave access shape identical to the
// 256-thread version: 4 row-groups x 16 col-lanes per wave) -----------------
__device__ __forceinline__ void load_tile_f4(const float* __restrict__ g, int tid, float4 r[2]) {
#pragma unroll
  for (int t = 0; t < 2; t++) {
    int q = tid + 512 * t;          // f4 index 0..1023
    int row = q >> 4, c4 = q & 15;  // 64 rows x 16 float4
    r[t] = ((const float4*)(g + (size_t)row * Nn))[c4];
  }
}
__device__ __forceinline__ void store_stage(float* __restrict__ s, int tid, const float4 r[2]) {
#pragma unroll
  for (int t = 0; t < 2; t++) {
    int q = tid + 512 * t;
    int row = q >> 4, c4 = q & 15;
    *((float4*)(s + row * LDV + c4 * 4)) = r[t];
  }
}
// acc -= Arows · Brows^T (64-deep), 2x4 frag at (tr*2.., tc+16*..)
// unroll 2 (NOT full): full unroll of 16 iters hoists ~96 float4 LDS loads,
// blowing past the 128-VGPR ceiling the compiler imposes on 512-thread WGs
// -> massive scratch spill (R1-R3: 10 GB/dispatch). 2 steps in flight keeps
// demand ~<100 regs while retaining load/FMA overlap.
__device__ __forceinline__ void mm_nt_sub(const float* __restrict__ sa, const float* __restrict__ sb,
                                          int tr, int tc, float acc[2][4]) {
#pragma unroll 2
  for (int k = 0; k < NB; k += 4) {
    float4 av[2], bv[4];
#pragma unroll
    for (int i = 0; i < 2; i++) av[i] = *(const float4*)(sa + (tr * 2 + i) * LDV + k);
#pragma unroll
    for (int j = 0; j < 4; j++) bv[j] = *(const float4*)(sb + (tc + 16 * j) * LDV + k);
#pragma unroll
    for (int i = 0; i < 2; i++)
#pragma unroll
      for (int j = 0; j < 4; j++)
        acc[i][j] -= av[i].x * bv[j].x + av[i].y * bv[j].y + av[i].z * bv[j].z + av[i].w * bv[j].w;
  }
}

// K1: gamma[b,d] = sum_t x[b,t,d]*w[b,t]; Nsum[b] = sum_t w[b,t]
__global__ __launch_bounds__(256) void k_gamma(const float* __restrict__ x,
                                               const float* __restrict__ w,
                                               float* __restrict__ gamma,
                                               float* __restrict__ Nsum) {
  int b = blockIdx.x, tid = threadIdx.x;
  const float2* xb = (const float2*)(x + (size_t)b * Tn * Nn);
  const float* wb = w + b * Tn;
  float gx = 0.f, gy = 0.f, ns = 0.f;
  for (int t = 0; t < Tn; t++) {
    float wt = wb[t];
    ns += wt;
    float2 v = xb[(size_t)t * 256 + tid];
    gx += v.x * wt;
    gy += v.y * wt;
  }
  float2 g2; g2.x = gx; g2.y = gy;
  ((float2*)(gamma + b * Nn))[tid] = g2;
  if (tid == 0) Nsum[b] = ns;
}

// K2: C = diag(exp(0.5*Dw)) * chol_w, full store with explicit zeros below diag
__global__ __launch_bounds__(256) void k_prepC(const float* __restrict__ Dw,
                                               const float* __restrict__ cholw,
                                               float* __restrict__ C) {
  int r = blockIdx.x, tid = threadIdx.x;
  float s = expf(0.5f * Dw[r]);
  for (int c = tid; c < Nn; c += 256)
    C[r * Nn + c] = (c >= r) ? s * cholw[r * Nn + c] : 0.f;
}

// K3: CCT = C*C^T. Upper 32x32 tiles (136) + the 8 below-diagonal tiles adjacent
// to the 64x64 diagonal blocks (needed by k_factor's full-tile reads).
__global__ __launch_bounds__(256) void k_cct(const float* __restrict__ C,
                                             float* __restrict__ CCT) {
  __shared__ float Ci[32][33];
  __shared__ float Cj[32][33];
  int tid = threadIdx.x;
  int idx = blockIdx.x, ti = 0, tj;
  if (idx < 136) {
    while (idx >= 16 - ti) { idx -= 16 - ti; ti++; }
    tj = ti + idx;
  } else {                 // lower sub-tile of 64x64 diag block j: (2j+1, 2j)
    ti = 2 * (idx - 136) + 1;
    tj = ti - 1;
  }
  int i0 = ti * 32, j0 = tj * 32;
  int m0 = (i0 > j0) ? i0 : j0;
  float acc[4] = {0.f, 0.f, 0.f, 0.f};
  int r = tid >> 3, c0 = tid & 7;
  for (int kt = m0; kt < Nn; kt += 32) {  // C rows are zero left of the diagonal
    __syncthreads();
    for (int q = tid; q < 1024; q += 256) {
      int rr = q >> 5, cc = q & 31;
      Ci[rr][cc] = C[(size_t)(i0 + rr) * Nn + kt + cc];
      Cj[rr][cc] = C[(size_t)(j0 + rr) * Nn + kt + cc];
    }
    __syncthreads();
    for (int k = 0; k < 32; k++) {
      float a = Ci[r][k];
#pragma unroll
      for (int j = 0; j < 4; j++) acc[j] += a * Cj[c0 + 8 * j][k];
    }
  }
#pragma unroll
  for (int j = 0; j < 4; j++)
    CCT[(size_t)(i0 + r) * Nn + j0 + c0 + 8 * j] = acc[j];
}

// K4 (left-looking, fused trsm): per batch b, reverse-Cholesky S = CCT + Nb*I = U U^T.
// 512 threads (8 waves -> 2 waves/SIMD; LDS caps us at 1 block/CU and grid=#CUs).
// Spill control: (1) unroll-2 inner k-loops keep live float4 count small;
// (2) native amdgpu_waves_per_eu(2) asks for the 256-reg budget matching the
// true 1-block/CU residency (launch_bounds' 2nd arg proved inert R2/R3).
__global__ __attribute__((amdgpu_waves_per_eu(2)))
__launch_bounds__(512) void k_factor(const float* __restrict__ CCT,
                                     const float* __restrict__ Nsum,
                                     float* __restrict__ AG) {
  const int b = blockIdx.x, tid = threadIdx.x;
  float* A = AG + (size_t)b * Nn * Nn;
  const float Nb = Nsum[b];
  __shared__ __align__(16) float sA[2][NB * LDV];
  __shared__ __align__(16) float sB[2][NB * LDV];
  __shared__ __align__(16) float sVd[NB * LDV];
  __shared__ float sAd[NB * LDA];
  const int tr = tid >> 4, tc = tid & 15;   // 32 row-groups x 16 col-lanes
  float4 ra[2], rb[2];

  for (int j = 7; j >= 0; j--) {
    const int nst = 7 - j;
    // ---------- diag tile: acc = CCT(j,j)+Nb*I - sum_k U(j,k)U(j,k)^T ----------
    float acc[2][4];
    {
      const float* T = CCT + TOFF(j, j);
#pragma unroll
      for (int i = 0; i < 2; i++) {
        const int r = tr * 2 + i;
#pragma unroll
        for (int jj = 0; jj < 4; jj++) {
          const int c = tc + 16 * jj;
          float v = T[(size_t)r * Nn + c];
          if (r == c) v += Nb;
          acc[i][jj] = v;
        }
      }
    }
    if (nst) load_tile_f4(A + TOFF(j, j + 1), tid, ra);
    __syncthreads();                       // previous phase done with sA/sB
    if (nst) store_stage(sA[0], tid, ra);
    __syncthreads();
    for (int kk = 0; kk < nst; kk++) {
      const int s = kk & 1;
      if (kk + 1 < nst) load_tile_f4(A + TOFF(j, j + 2 + kk), tid, ra);
      mm_nt_sub(sA[s], sA[s], tr, tc, acc);
      if (kk + 1 < nst) store_stage(sA[s ^ 1], tid, ra);
      __syncthreads();
    }
    // deposit to sAd (full tile defined)
#pragma unroll
    for (int i = 0; i < 2; i++)
#pragma unroll
      for (int jj = 0; jj < 4; jj++)
        sAd[(tr * 2 + i) * LDA + tc + 16 * jj] = acc[i][jj];
    __syncthreads();
    // reverse Cholesky of 64x64 (upper): columns high->low
    for (int c = NB - 1; c >= 0; c--) {
      float dcc = sAd[c * LDA + c];
      float rs = rsqrtf(dcc);
      if (tid < c) sAd[tid * LDA + c] *= rs;
      else if (tid == c) sAd[c * LDA + c] = dcc * rs;
      __syncthreads();
      int jj = tid & 63, i0 = tid >> 6;     // i0 0..7 with 512 threads
      if (jj < c) {
        float ujc = sAd[jj * LDA + c];
        for (int i = i0; i <= jj; i += 8) sAd[i * LDA + jj] -= sAd[i * LDA + c] * ujc;
      }
      __syncthreads();
    }
    // Vd = Ujj^-1: zero, then barrier-free per-thread column back-substitution
    for (int q = tid; q < NB * LDV; q += 512) sVd[q] = 0.f;
    __syncthreads();
    if (tid < NB) {
      const int c = tid;  // column c: rows r=c..0, deps are thread-private
      for (int r = c; r >= 0; r--) {
        float s2 = (r == c) ? 1.f : 0.f;
        for (int k = r + 1; k <= c; k++) s2 -= sAd[r * LDA + k] * sVd[k * LDV + c];
        sVd[r * LDV + c] = s2 / sAd[r * LDA + r];
      }
    }
    __syncthreads();
    // stash Vd in a dead lower-triangle tile for k_solve
    {
      const int vr = (j < 7) ? 7 : 6, vc = (j < 7) ? j : 0;
      float* Vt = A + TOFF(vr, vc);
      for (int q = tid; q < NB * NB; q += 512) {
        int r = q >> 6, c = q & 63;
        Vt[(size_t)r * Nn + c] = sVd[r * LDV + c];
      }
    }
    // ---------- off-diag tiles: U(i,j) = (CCT(i,j) - sum_k U(i,k)U(j,k)^T) Vd^T ----------
    for (int i = j - 1; i >= 0; i--) {
      float acc2[2][4];
      {
        const float* T = CCT + TOFF(i, j);
#pragma unroll
        for (int ii = 0; ii < 2; ii++)
#pragma unroll
          for (int jj = 0; jj < 4; jj++)
            acc2[ii][jj] = T[(size_t)(tr * 2 + ii) * Nn + tc + 16 * jj];
      }
      if (nst) {
        load_tile_f4(A + TOFF(i, j + 1), tid, ra);
        load_tile_f4(A + TOFF(j, j + 1), tid, rb);
      }
      __syncthreads();                     // prev readers of sA/sB done
      if (nst) { store_stage(sA[0], tid, ra); store_stage(sB[0], tid, rb); }
      __syncthreads();
      for (int kk = 0; kk < nst; kk++) {
        const int s = kk & 1;
        if (kk + 1 < nst) {
          load_tile_f4(A + TOFF(i, j + 2 + kk), tid, ra);
          load_tile_f4(A + TOFF(j, j + 2 + kk), tid, rb);
        }
        mm_nt_sub(sA[s], sB[s], tr, tc, acc2);
        if (kk + 1 < nst) { store_stage(sA[s ^ 1], tid, ra); store_stage(sB[s ^ 1], tid, rb); }
        __syncthreads();
      }
      // trsm via round trip: X = acc2 · Vd^T
#pragma unroll
      for (int ii = 0; ii < 2; ii++)
#pragma unroll
        for (int jj = 0; jj < 4; jj++)
          sA[0][(tr * 2 + ii) * LDV + tc + 16 * jj] = acc2[ii][jj];
      __syncthreads();
      {
        float out[2][4] = {};
#pragma unroll 2
        for (int k = 0; k < NB; k += 4) {
          float4 av[2], bv[4];
#pragma unroll
          for (int ii = 0; ii < 2; ii++) av[ii] = *(const float4*)(sA[0] + (tr * 2 + ii) * LDV + k);
#pragma unroll
          for (int jj = 0; jj < 4; jj++) bv[jj] = *(const float4*)(sVd + (tc + 16 * jj) * LDV + k);
#pragma unroll
          for (int ii = 0; ii < 2; ii++)
#pragma unroll
            for (int jj = 0; jj < 4; jj++)
              out[ii][jj] += av[ii].x * bv[jj].x + av[ii].y * bv[jj].y +
                             av[ii].z * bv[jj].z + av[ii].w * bv[jj].w;
        }
        float* X = A + TOFF(i, j);
#pragma unroll
        for (int ii = 0; ii < 2; ii++)
#pragma unroll
          for (int jj = 0; jj < 4; jj++)
            X[(size_t)(tr * 2 + ii) * Nn + tc + 16 * jj] = out[ii][jj];
      }
      __syncthreads();                     // before next tile reuses sA[0]
    }
  }
}

// K5: per batch, solve U*G = C (G upper) in place over U; Vd read from stash.
// 512 threads, 2x4 fragments, unroll-2 inner loops (same spill rationale).
__global__ __attribute__((amdgpu_waves_per_eu(2)))
__launch_bounds__(512) void k_solve(const float* __restrict__ C,
                                    float* __restrict__ AG) {
  const int b = blockIdx.x, tid = threadIdx.x;
  float* A = AG + (size_t)b * Nn * Nn;
  __shared__ __align__(16) float sA[2][NB * LDV];
  __shared__ __align__(16) float sB[2][NB * LDV];
  __shared__ __align__(16) float sVd[NB * LDV];
  const int tr = tid >> 4, tc = tid & 15;
  float4 ra[2], rb[2];
  for (int R = 7; R >= 0; R--) {
    {
      const int vr = (R < 7) ? 7 : 6, vc = (R < 7) ? R : 0;
      const float* Vt = A + TOFF(vr, vc);
      __syncthreads();                     // prev R's readers of sVd done
      for (int q = tid; q < NB * NB; q += 512) {
        int r = q >> 6, c = q & 63;
        sVd[r * LDV + c] = Vt[(size_t)r * Nn + c];
      }
      __syncthreads();
    }
    for (int J = 7; J >= R; J--) {
      const int nst = J - R;
      float acc[2][4];
      {
        const float* T = C + TOFF(R, J);
#pragma unroll
        for (int ii = 0; ii < 2; ii++)
#pragma unroll
          for (int jj = 0; jj < 4; jj++)
            acc[ii][jj] = T[(size_t)(tr * 2 + ii) * Nn + tc + 16 * jj];
      }
      if (nst) {
        load_tile_f4(A + TOFF(R, R + 1), tid, ra);
        load_tile_f4(A + TOFF(R + 1, J), tid, rb);
      }
      __syncthreads();
      if (nst) { store_stage(sA[0], tid, ra); store_stage(sB[0], tid, rb); }
      __syncthreads();
      for (int kk = 0; kk < nst; kk++) {
        const int s = kk & 1;
        if (kk + 1 < nst) {
          load_tile_f4(A + TOFF(R, R + 2 + kk), tid, ra);
          load_tile_f4(A + TOFF(R + 2 + kk, J), tid, rb);
        }
        // acc -= U(R,K) * G(K,J)   (A·B: b-side scalar reads, conflict-free)
#pragma unroll 2
        for (int k = 0; k < NB; k += 4) {
          float a4[2][4];
#pragma unroll
          for (int ii = 0; ii < 2; ii++) {
            float4 t = *(const float4*)(sA[s] + (tr * 2 + ii) * LDV + k);
            a4[ii][0] = t.x; a4[ii][1] = t.y; a4[ii][2] = t.z; a4[ii][3] = t.w;
          }
#pragma unroll
          for (int k2 = 0; k2 < 4; k2++) {
            float bb[4];
#pragma unroll
            for (int jj = 0; jj < 4; jj++) bb[jj] = sB[s][(k + k2) * LDV + tc + 16 * jj];
#pragma unroll
            for (int ii = 0; ii < 2; ii++)
#pragma unroll
              for (int jj = 0; jj < 4; jj++) acc[ii][jj] -= a4[ii][k2] * bb[jj];
          }
        }
        if (kk + 1 < nst) { store_stage(sA[s ^ 1], tid, ra); store_stage(sB[s ^ 1], tid, rb); }
        __syncthreads();
      }
      // round trip: temp -> sA[0]; G(R,J) = Vd * temp
#pragma unroll
      for (int ii = 0; ii < 2; ii++)
#pragma unroll
        for (int jj = 0; jj < 4; jj++)
          sA[0][(tr * 2 + ii) * LDV + tc + 16 * jj] = acc[ii][jj];
      __syncthreads();
      {
        float out[2][4] = {};
#pragma unroll 2
        for (int k = 0; k < NB; k += 4) {
          float v4[2][4];
#pragma unroll
          for (int ii = 0; ii < 2; ii++) {
            float4 t = *(const float4*)(sVd + (tr * 2 + ii) * LDV + k);
            v4[ii][0] = t.x; v4[ii][1] = t.y; v4[ii][2] = t.z; v4[ii][3] = t.w;
          }
#pragma unroll
          for (int k2 = 0; k2 < 4; k2++) {
            float bb[4];
#pragma unroll
            for (int jj = 0; jj < 4; jj++) bb[jj] = sA[0][(k + k2) * LDV + tc + 16 * jj];
#pragma unroll
            for (int ii = 0; ii < 2; ii++)
#pragma unroll
              for (int jj = 0; jj < 4; jj++) out[ii][jj] += v4[ii][k2] * bb[jj];
          }
        }
        float* G = A + TOFF(R, J);
#pragma unroll
        for (int ii = 0; ii < 2; ii++)
#pragma unroll
          for (int jj = 0; jj < 4; jj++)
            G[(size_t)(tr * 2 + ii) * Nn + tc + 16 * jj] = out[ii][jj];
      }
      __syncthreads();
    }
  }
}

// K6: y = G*gamma, mu = G^T y, logvar = 2 log diag(G), chol = G/diag rows,
// zero strict lower. One row per wave; barrier-free shuffle reduce. 8 waves.
__global__ __launch_bounds__(512) void k_finish(const float* __restrict__ gam,
                                                float* __restrict__ mu,
                                                float* __restrict__ logvar,
                                                float* __restrict__ cholG) {
  int b = blockIdx.x, tid = threadIdx.x;
  float* A = cholG + (size_t)b * Nn * Nn;
  __shared__ float gsh[Nn];
  __shared__ float mup[8][Nn];
  for (int c = tid; c < Nn; c += 512) gsh[c] = gam[b * Nn + c];
  __syncthreads();
  int w = tid >> 6, l = tid & 63;
  float mua[8] = {0.f, 0.f, 0.f, 0.f, 0.f, 0.f, 0.f, 0.f};
  for (int i = w; i < Nn; i += 8) {
    const size_t rowo = (size_t)i * Nn;
    float v[8];
    float s = 0.f;
#pragma unroll
    for (int j = 0; j < 8; j++) {
      int c = (j << 6) + l;
      v[j] = A[rowo + c];
      if (c >= i) s += v[j] * gsh[c];
    }
#pragma unroll
    for (int off = 32; off > 0; off >>= 1) s += __shfl_xor(s, off, 64);
    float d = A[rowo + i];
    float rinv = 1.f / d;
    if (l == 0) logvar[b * Nn + i] = 2.f * logf(d);
#pragma unroll
    for (int j = 0; j < 8; j++) {
      int c = (j << 6) + l;
      if (c >= i) mua[j] += v[j] * s;
      float o = (c > i) ? v[j] * rinv : (c == i ? 1.f : 0.f);
      A[rowo + c] = o;
    }
  }
#pragma unroll
  for (int j = 0; j < 8; j++) mup[w][(j << 6) + l] = mua[j];
  __syncthreads();
  for (int c = tid; c < Nn; c += 512)
    mu[b * Nn + c] = mup[0][c] + mup[1][c] + mup[2][c] + mup[3][c] +
                     mup[4][c] + mup[5][c] + mup[6][c] + mup[7][c];
}

extern "C" void kernel_launch(void* const* d_in, const int* in_sizes, int n_in,
                              void* d_out, int out_size, void* d_ws, size_t ws_size,
                              hipStream_t stream) {
  const float* x = (const float*)d_in[0];
  const float* w = (const float*)d_in[1];
  const float* Dw = (const float*)d_in[2];
  const float* cholw = (const float*)d_in[3];
  float* out = (float*)d_out;
  float* mu = out;                  // [B,512]
  float* logvar = out + Bn * Nn;    // [B,512]
  float* chol = out + 2 * Bn * Nn;  // [B,512,512] scratch: U (+Vd stash) -> G -> final
  float* gamma = mu;                // consumed before mu written
  float* Nsum = logvar;             // consumed before logvar written
  float* Cm = (float*)d_ws;
  float* CCT = Cm + Nn * Nn;
  (void)in_sizes; (void)n_in; (void)out_size; (void)ws_size;

  k_gamma<<<Bn, 256, 0, stream>>>(x, w, gamma, Nsum);
  k_prepC<<<Nn, 256, 0, stream>>>(Dw, cholw, Cm);
  k_cct<<<144, 256, 0, stream>>>(Cm, CCT);
  k_factor<<<Bn, 512, 0, stream>>>(CCT, Nsum, chol);
  k_solve<<<Bn, 512, 0, stream>>>(Cm, chol);
  k_finish<<<Bn, 512, 0, stream>>>(gamma, mu, logvar, chol);
}

// Round 5
// 2255.122 us; speedup vs baseline: 2.8624x; 1.0217x over previous
//
#include <hip/hip_runtime.h>
#include <math.h>

#define Bn 256
#define Tn 300
#define Nn 512
#define NB 64
#define LDV 68   // stream/Vd pitch: breaks 16-row stride conflicts
#define LDA 65   // diag-Cholesky pitch

#define TOFF(i,j) ((size_t)((i)*NB)*Nn + (size_t)(j)*NB)

// ---- helpers (512-thread tile ops) ----------------------------------------
__device__ __forceinline__ void load_tile_f4(const float* __restrict__ g, int tid, float4 r[2]) {
#pragma unroll
  for (int t = 0; t < 2; t++) {
    int q = tid + 512 * t;          // f4 index 0..1023
    int row = q >> 4, c4 = q & 15;  // 64 rows x 16 float4
    r[t] = ((const float4*)(g + (size_t)row * Nn))[c4];
  }
}
__device__ __forceinline__ void store_stage(float* __restrict__ s, int tid, const float4 r[2]) {
#pragma unroll
  for (int t = 0; t < 2; t++) {
    int q = tid + 512 * t;
    int row = q >> 4, c4 = q & 15;
    *((float4*)(s + row * LDV + c4 * 4)) = r[t];
  }
}
// acc -= Arows · Brows^T (64-deep), 2x4 frag at (tr*2.., tc+16*..)
// unroll 2 (NOT full): full unroll spills past the 128-VGPR ceiling on
// 512-thread WGs (R1-R3: 10 GB scratch/dispatch). Verified fix in R4.
__device__ __forceinline__ void mm_nt_sub(const float* __restrict__ sa, const float* __restrict__ sb,
                                          int tr, int tc, float acc[2][4]) {
#pragma unroll 2
  for (int k = 0; k < NB; k += 4) {
    float4 av[2], bv[4];
#pragma unroll
    for (int i = 0; i < 2; i++) av[i] = *(const float4*)(sa + (tr * 2 + i) * LDV + k);
#pragma unroll
    for (int j = 0; j < 4; j++) bv[j] = *(const float4*)(sb + (tc + 16 * j) * LDV + k);
#pragma unroll
    for (int i = 0; i < 2; i++)
#pragma unroll
      for (int j = 0; j < 4; j++)
        acc[i][j] -= av[i].x * bv[j].x + av[i].y * bv[j].y + av[i].z * bv[j].z + av[i].w * bv[j].w;
  }
}

// K1: gamma[b,d] = sum_t x[b,t,d]*w[b,t]; Nsum[b] = sum_t w[b,t]
__global__ __launch_bounds__(256) void k_gamma(const float* __restrict__ x,
                                               const float* __restrict__ w,
                                               float* __restrict__ gamma,
                                               float* __restrict__ Nsum) {
  int b = blockIdx.x, tid = threadIdx.x;
  const float2* xb = (const float2*)(x + (size_t)b * Tn * Nn);
  const float* wb = w + b * Tn;
  float gx = 0.f, gy = 0.f, ns = 0.f;
#pragma unroll 4
  for (int t = 0; t < Tn; t++) {
    float wt = wb[t];
    ns += wt;
    float2 v = xb[(size_t)t * 256 + tid];
    gx += v.x * wt;
    gy += v.y * wt;
  }
  float2 g2; g2.x = gx; g2.y = gy;
  ((float2*)(gamma + b * Nn))[tid] = g2;
  if (tid == 0) Nsum[b] = ns;
}

// K2: C = diag(exp(0.5*Dw)) * chol_w, full store with explicit zeros below diag
__global__ __launch_bounds__(256) void k_prepC(const float* __restrict__ Dw,
                                               const float* __restrict__ cholw,
                                               float* __restrict__ C) {
  int r = blockIdx.x, tid = threadIdx.x;
  float s = expf(0.5f * Dw[r]);
  for (int c = tid; c < Nn; c += 256)
    C[r * Nn + c] = (c >= r) ? s * cholw[r * Nn + c] : 0.f;
}

// K3: CCT = C*C^T. Upper 32x32 tiles (136) + the 8 below-diagonal tiles adjacent
// to the 64x64 diagonal blocks (needed by k_factor's full-tile reads).
__global__ __launch_bounds__(256) void k_cct(const float* __restrict__ C,
                                             float* __restrict__ CCT) {
  __shared__ float Ci[32][33];
  __shared__ float Cj[32][33];
  int tid = threadIdx.x;
  int idx = blockIdx.x, ti = 0, tj;
  if (idx < 136) {
    while (idx >= 16 - ti) { idx -= 16 - ti; ti++; }
    tj = ti + idx;
  } else {                 // lower sub-tile of 64x64 diag block j: (2j+1, 2j)
    ti = 2 * (idx - 136) + 1;
    tj = ti - 1;
  }
  int i0 = ti * 32, j0 = tj * 32;
  int m0 = (i0 > j0) ? i0 : j0;
  float acc[4] = {0.f, 0.f, 0.f, 0.f};
  int r = tid >> 3, c0 = tid & 7;
  for (int kt = m0; kt < Nn; kt += 32) {  // C rows are zero left of the diagonal
    __syncthreads();
    for (int q = tid; q < 1024; q += 256) {
      int rr = q >> 5, cc = q & 31;
      Ci[rr][cc] = C[(size_t)(i0 + rr) * Nn + kt + cc];
      Cj[rr][cc] = C[(size_t)(j0 + rr) * Nn + kt + cc];
    }
    __syncthreads();
    for (int k = 0; k < 32; k++) {
      float a = Ci[r][k];
#pragma unroll
      for (int j = 0; j < 4; j++) acc[j] += a * Cj[c0 + 8 * j][k];
    }
  }
#pragma unroll
  for (int j = 0; j < 4; j++)
    CCT[(size_t)(i0 + r) * Nn + j0 + c0 + 8 * j] = acc[j];
}

// K4 (left-looking, fused trsm): per batch b, reverse-Cholesky S = CCT + Nb*I = U U^T.
// R5: outer-product deferred-scale Cholesky (1 barrier/column + 2-barrier final
// scale, vs 2 barriers/column): the 1024 tiny barrier micro-phases per block
// were the dominant cost (insensitive to occupancy doubling R0->R4).
// A[i][j] -= A[i][c]*A[j][c]/D_c is algebraically identical to the pre-scaled
// update; columns are scaled by rsqrt(D_c) once at the end.
__global__ __attribute__((amdgpu_waves_per_eu(2)))
__launch_bounds__(512) void k_factor(const float* __restrict__ CCT,
                                     const float* __restrict__ Nsum,
                                     float* __restrict__ AG) {
  const int b = blockIdx.x, tid = threadIdx.x;
  float* A = AG + (size_t)b * Nn * Nn;
  const float Nb = Nsum[b];
  __shared__ __align__(16) float sA[2][NB * LDV];
  __shared__ __align__(16) float sB[2][NB * LDV];
  __shared__ __align__(16) float sVd[NB * LDV];
  __shared__ float sAd[NB * LDA];
  __shared__ float sdg[NB];
  const int tr = tid >> 4, tc = tid & 15;   // 32 row-groups x 16 col-lanes
  float4 ra[2], rb[2];

  for (int j = 7; j >= 0; j--) {
    const int nst = 7 - j;
    // ---------- diag tile: acc = CCT(j,j)+Nb*I - sum_k U(j,k)U(j,k)^T ----------
    float acc[2][4];
    {
      const float* T = CCT + TOFF(j, j);
#pragma unroll
      for (int i = 0; i < 2; i++) {
        const int r = tr * 2 + i;
#pragma unroll
        for (int jj = 0; jj < 4; jj++) {
          const int c = tc + 16 * jj;
          float v = T[(size_t)r * Nn + c];
          if (r == c) v += Nb;
          acc[i][jj] = v;
        }
      }
    }
    // NOTE: no barrier before store_stage: previous phase ended with a barrier,
    // and no other wave reads sA between there and here.
    if (nst) {
      load_tile_f4(A + TOFF(j, j + 1), tid, ra);
      store_stage(sA[0], tid, ra);
    }
    __syncthreads();
    for (int kk = 0; kk < nst; kk++) {
      const int s = kk & 1;
      if (kk + 1 < nst) load_tile_f4(A + TOFF(j, j + 2 + kk), tid, ra);
      mm_nt_sub(sA[s], sA[s], tr, tc, acc);
      if (kk + 1 < nst) store_stage(sA[s ^ 1], tid, ra);
      __syncthreads();
    }
    // deposit to sAd (full tile defined)
#pragma unroll
    for (int i = 0; i < 2; i++)
#pragma unroll
      for (int jj = 0; jj < 4; jj++)
        sAd[(tr * 2 + i) * LDA + tc + 16 * jj] = acc[i][jj];
    __syncthreads();
    // reverse Cholesky (upper, columns high->low), outer-product deferred-scale:
    // one barrier per column.
    {
      const int jj = tid & 63, i0 = tid >> 6;  // i0 = wave id (uniform per wave)
      for (int c = NB - 1; c > 0; --c) {
        float invd = 1.0f / sAd[c * LDA + c];   // broadcast read, stable this phase
        if (jj < c) {
          float t = sAd[jj * LDA + c] * invd;   // A[jj][c] (unscaled)
          for (int i = i0; i <= jj; i += 8)
            sAd[i * LDA + jj] -= sAd[i * LDA + c] * t;
        }
        __syncthreads();
      }
      // final scale: U[i][c] = A[i][c] * rsqrt(D_c); diag becomes sqrt(D_c)
      if (tid < NB) sdg[tid] = rsqrtf(sAd[tid * LDA + tid]);
      __syncthreads();
      for (int q = tid; q < NB * NB; q += 512) {
        int r = q >> 6, cc = q & 63;
        if (r <= cc) sAd[r * LDA + cc] *= sdg[cc];
      }
      __syncthreads();
    }
    // Vd = Ujj^-1: zero, then barrier-free per-thread column back-substitution
    for (int q = tid; q < NB * LDV; q += 512) sVd[q] = 0.f;
    __syncthreads();
    if (tid < NB) {
      const int c = tid;  // column c: rows r=c..0, deps are thread-private
      for (int r = c; r >= 0; r--) {
        float s2 = (r == c) ? 1.f : 0.f;
        for (int k = r + 1; k <= c; k++) s2 -= sAd[r * LDA + k] * sVd[k * LDV + c];
        sVd[r * LDV + c] = s2 / sAd[r * LDA + r];
      }
    }
    __syncthreads();
    // stash Vd in a dead lower-triangle tile for k_solve
    {
      const int vr = (j < 7) ? 7 : 6, vc = (j < 7) ? j : 0;
      float* Vt = A + TOFF(vr, vc);
      for (int q = tid; q < NB * NB; q += 512) {
        int r = q >> 6, c = q & 63;
        Vt[(size_t)r * Nn + c] = sVd[r * LDV + c];
      }
    }
    // ---------- off-diag tiles: U(i,j) = (CCT(i,j) - sum_k U(i,k)U(j,k)^T) Vd^T ----------
    for (int i = j - 1; i >= 0; i--) {
      float acc2[2][4];
      {
        const float* T = CCT + TOFF(i, j);
#pragma unroll
        for (int ii = 0; ii < 2; ii++)
#pragma unroll
          for (int jj = 0; jj < 4; jj++)
            acc2[ii][jj] = T[(size_t)(tr * 2 + ii) * Nn + tc + 16 * jj];
      }
      // no barrier before store_stage (previous phase ended with a barrier;
      // stash only touches sVd/global, loads touch global)
      if (nst) {
        load_tile_f4(A + TOFF(i, j + 1), tid, ra);
        load_tile_f4(A + TOFF(j, j + 1), tid, rb);
        store_stage(sA[0], tid, ra);
        store_stage(sB[0], tid, rb);
      }
      __syncthreads();
      for (int kk = 0; kk < nst; kk++) {
        const int s = kk & 1;
        if (kk + 1 < nst) {
          load_tile_f4(A + TOFF(i, j + 2 + kk), tid, ra);
          load_tile_f4(A + TOFF(j, j + 2 + kk), tid, rb);
        }
        mm_nt_sub(sA[s], sB[s], tr, tc, acc2);
        if (kk + 1 < nst) { store_stage(sA[s ^ 1], tid, ra); store_stage(sB[s ^ 1], tid, rb); }
        __syncthreads();
      }
      // trsm via round trip: X = acc2 · Vd^T
#pragma unroll
      for (int ii = 0; ii < 2; ii++)
#pragma unroll
        for (int jj = 0; jj < 4; jj++)
          sA[0][(tr * 2 + ii) * LDV + tc + 16 * jj] = acc2[ii][jj];
      __syncthreads();
      {
        float out[2][4] = {};
#pragma unroll 2
        for (int k = 0; k < NB; k += 4) {
          float4 av[2], bv[4];
#pragma unroll
          for (int ii = 0; ii < 2; ii++) av[ii] = *(const float4*)(sA[0] + (tr * 2 + ii) * LDV + k);
#pragma unroll
          for (int jj = 0; jj < 4; jj++) bv[jj] = *(const float4*)(sVd + (tc + 16 * jj) * LDV + k);
#pragma unroll
          for (int ii = 0; ii < 2; ii++)
#pragma unroll
            for (int jj = 0; jj < 4; jj++)
              out[ii][jj] += av[ii].x * bv[jj].x + av[ii].y * bv[jj].y +
                             av[ii].z * bv[jj].z + av[ii].w * bv[jj].w;
        }
        float* X = A + TOFF(i, j);
#pragma unroll
        for (int ii = 0; ii < 2; ii++)
#pragma unroll
          for (int jj = 0; jj < 4; jj++)
            X[(size_t)(tr * 2 + ii) * Nn + tc + 16 * jj] = out[ii][jj];
      }
      __syncthreads();                     // before next tile reuses sA[0]
    }
  }
}

// K5: per batch, solve U*G = C (G upper) in place over U; Vd read from stash.
__global__ __attribute__((amdgpu_waves_per_eu(2)))
__launch_bounds__(512) void k_solve(const float* __restrict__ C,
                                    float* __restrict__ AG) {
  const int b = blockIdx.x, tid = threadIdx.x;
  float* A = AG + (size_t)b * Nn * Nn;
  __shared__ __align__(16) float sA[2][NB * LDV];
  __shared__ __align__(16) float sB[2][NB * LDV];
  __shared__ __align__(16) float sVd[NB * LDV];
  const int tr = tid >> 4, tc = tid & 15;
  float4 ra[2], rb[2];
  for (int R = 7; R >= 0; R--) {
    {
      const int vr = (R < 7) ? 7 : 6, vc = (R < 7) ? R : 0;
      const float* Vt = A + TOFF(vr, vc);
      __syncthreads();                     // prev R's readers of sVd done
      for (int q = tid; q < NB * NB; q += 512) {
        int r = q >> 6, c = q & 63;
        sVd[r * LDV + c] = Vt[(size_t)r * Nn + c];
      }
      __syncthreads();
    }
    for (int J = 7; J >= R; J--) {
      const int nst = J - R;
      float acc[2][4];
      {
        const float* T = C + TOFF(R, J);
#pragma unroll
        for (int ii = 0; ii < 2; ii++)
#pragma unroll
          for (int jj = 0; jj < 4; jj++)
            acc[ii][jj] = T[(size_t)(tr * 2 + ii) * Nn + tc + 16 * jj];
      }
      if (nst) {
        load_tile_f4(A + TOFF(R, R + 1), tid, ra);
        load_tile_f4(A + TOFF(R + 1, J), tid, rb);
      }
      __syncthreads();
      if (nst) { store_stage(sA[0], tid, ra); store_stage(sB[0], tid, rb); }
      __syncthreads();
      for (int kk = 0; kk < nst; kk++) {
        const int s = kk & 1;
        if (kk + 1 < nst) {
          load_tile_f4(A + TOFF(R, R + 2 + kk), tid, ra);
          load_tile_f4(A + TOFF(R + 2 + kk, J), tid, rb);
        }
        // acc -= U(R,K) * G(K,J)   (A·B: b-side scalar reads, conflict-free)
#pragma unroll 2
        for (int k = 0; k < NB; k += 4) {
          float a4[2][4];
#pragma unroll
          for (int ii = 0; ii < 2; ii++) {
            float4 t = *(const float4*)(sA[s] + (tr * 2 + ii) * LDV + k);
            a4[ii][0] = t.x; a4[ii][1] = t.y; a4[ii][2] = t.z; a4[ii][3] = t.w;
          }
#pragma unroll
          for (int k2 = 0; k2 < 4; k2++) {
            float bb[4];
#pragma unroll
            for (int jj = 0; jj < 4; jj++) bb[jj] = sB[s][(k + k2) * LDV + tc + 16 * jj];
#pragma unroll
            for (int ii = 0; ii < 2; ii++)
#pragma unroll
              for (int jj = 0; jj < 4; jj++) acc[ii][jj] -= a4[ii][k2] * bb[jj];
          }
        }
        if (kk + 1 < nst) { store_stage(sA[s ^ 1], tid, ra); store_stage(sB[s ^ 1], tid, rb); }
        __syncthreads();
      }
      // round trip: temp -> sA[0]; G(R,J) = Vd * temp
#pragma unroll
      for (int ii = 0; ii < 2; ii++)
#pragma unroll
        for (int jj = 0; jj < 4; jj++)
          sA[0][(tr * 2 + ii) * LDV + tc + 16 * jj] = acc[ii][jj];
      __syncthreads();
      {
        float out[2][4] = {};
#pragma unroll 2
        for (int k = 0; k < NB; k += 4) {
          float v4[2][4];
#pragma unroll
          for (int ii = 0; ii < 2; ii++) {
            float4 t = *(const float4*)(sVd + (tr * 2 + ii) * LDV + k);
            v4[ii][0] = t.x; v4[ii][1] = t.y; v4[ii][2] = t.z; v4[ii][3] = t.w;
          }
#pragma unroll
          for (int k2 = 0; k2 < 4; k2++) {
            float bb[4];
#pragma unroll
            for (int jj = 0; jj < 4; jj++) bb[jj] = sA[0][(k + k2) * LDV + tc + 16 * jj];
#pragma unroll
            for (int ii = 0; ii < 2; ii++)
#pragma unroll
              for (int jj = 0; jj < 4; jj++) out[ii][jj] += v4[ii][k2] * bb[jj];
          }
        }
        float* G = A + TOFF(R, J);
#pragma unroll
        for (int ii = 0; ii < 2; ii++)
#pragma unroll
          for (int jj = 0; jj < 4; jj++)
            G[(size_t)(tr * 2 + ii) * Nn + tc + 16 * jj] = out[ii][jj];
      }
      __syncthreads();
    }
  }
}

// K6: y = G*gamma, mu = G^T y, logvar = 2 log diag(G), chol = G/diag rows,
// zero strict lower. One row per wave; barrier-free shuffle reduce. 8 waves.
__global__ __launch_bounds__(512) void k_finish(const float* __restrict__ gam,
                                                float* __restrict__ mu,
                                                float* __restrict__ logvar,
                                                float* __restrict__ cholG) {
  int b = blockIdx.x, tid = threadIdx.x;
  float* A = cholG + (size_t)b * Nn * Nn;
  __shared__ float gsh[Nn];
  __shared__ float mup[8][Nn];
  for (int c = tid; c < Nn; c += 512) gsh[c] = gam[b * Nn + c];
  __syncthreads();
  int w = tid >> 6, l = tid & 63;
  float mua[8] = {0.f, 0.f, 0.f, 0.f, 0.f, 0.f, 0.f, 0.f};
  for (int i = w; i < Nn; i += 8) {
    const size_t rowo = (size_t)i * Nn;
    float v[8];
    float s = 0.f;
#pragma unroll
    for (int j = 0; j < 8; j++) {
      int c = (j << 6) + l;
      v[j] = A[rowo + c];
      if (c >= i) s += v[j] * gsh[c];
    }
#pragma unroll
    for (int off = 32; off > 0; off >>= 1) s += __shfl_xor(s, off, 64);
    float d = A[rowo + i];
    float rinv = 1.f / d;
    if (l == 0) logvar[b * Nn + i] = 2.f * logf(d);
#pragma unroll
    for (int j = 0; j < 8; j++) {
      int c = (j << 6) + l;
      if (c >= i) mua[j] += v[j] * s;
      float o = (c > i) ? v[j] * rinv : (c == i ? 1.f : 0.f);
      A[rowo + c] = o;
    }
  }
#pragma unroll
  for (int j = 0; j < 8; j++) mup[w][(j << 6) + l] = mua[j];
  __syncthreads();
  for (int c = tid; c < Nn; c += 512)
    mu[b * Nn + c] = mup[0][c] + mup[1][c] + mup[2][c] + mup[3][c] +
                     mup[4][c] + mup[5][c] + mup[6][c] + mup[7][c];
}

extern "C" void kernel_launch(void* const* d_in, const int* in_sizes, int n_in,
                              void* d_out, int out_size, void* d_ws, size_t ws_size,
                              hipStream_t stream) {
  const float* x = (const float*)d_in[0];
  const float* w = (const float*)d_in[1];
  const float* Dw = (const float*)d_in[2];
  const float* cholw = (const float*)d_in[3];
  float* out = (float*)d_out;
  float* mu = out;                  // [B,512]
  float* logvar = out + Bn * Nn;    // [B,512]
  float* chol = out + 2 * Bn * Nn;  // [B,512,512] scratch: U (+Vd stash) -> G -> final
  float* gamma = mu;                // consumed before mu written
  float* Nsum = logvar;             // consumed before logvar written
  float* Cm = (float*)d_ws;
  float* CCT = Cm + Nn * Nn;
  (void)in_sizes; (void)n_in; (void)out_size; (void)ws_size;

  k_gamma<<<Bn, 256, 0, stream>>>(x, w, gamma, Nsum);
  k_prepC<<<Nn, 256, 0, stream>>>(Dw, cholw, Cm);
  k_cct<<<144, 256, 0, stream>>>(Cm, CCT);
  k_factor<<<Bn, 512, 0, stream>>>(CCT, Nsum, chol);
  k_solve<<<Bn, 512, 0, stream>>>(Cm, chol);
  k_finish<<<Bn, 512, 0, stream>>>(gamma, mu, logvar, chol);
}